// Round 5
// baseline (49.583 us; speedup 1.0000x reference)
//
#include <hip/hip_runtime.h>
#include <hip/hip_bf16.h>

#define NPTS  262144
#define CIN   16
#define COUT  32
#define NTAPS 27
#define BLK   256
#define DEPTH 8             // gathers in flight per wave (ring buffers)

#define WIMG_SHORTS (NTAPS * 512)     // 13824 shorts = 27648 B
#define WIMG_PAD    14336             // pad to 28672 B (7 x 4096) for copy loop
#define FEATB_OFF   32768             // byte offset of bf16 features in ws

typedef __attribute__((ext_vector_type(8)))  short short8v;   // 8 bf16 (4 VGPRs)
typedef __attribute__((ext_vector_type(16))) float f32x16;    // MFMA accumulator

// Fused prep: blocks 0..4095 convert features fp32->bf16 (4 floats/thread);
// block 4096 packs the W-fragment LDS image (bf16) into ws.
__global__ __launch_bounds__(256) void prep_kernel(
    const float* __restrict__ feat, const float* __restrict__ Wg,
    short* __restrict__ wimg, __hip_bfloat16* __restrict__ fb)
{
    if (blockIdx.x < NPTS * CIN / 4 / 256) {
        const int i = blockIdx.x * 256 + threadIdx.x;
        const float4 x = ((const float4*)feat)[i];
        __hip_bfloat162* o = (__hip_bfloat162*)fb;
        o[2 * i]     = __float22bfloat162_rn(float2{x.x, x.y});
        o[2 * i + 1] = __float22bfloat162_rn(float2{x.z, x.w});
    } else {
        // wimg[tap*512 + ln*8 + e] = bf16(W[tap][(ln>>5)*8+e][ln&31])
        for (int i = threadIdx.x; i < WIMG_PAD; i += 256) {
            short v = 0;
            if (i < WIMG_SHORTS) {
                const int tap  = i >> 9;
                const int r    = i & 511;
                const int ln   = r >> 3;
                const int e    = r & 7;
                const int cin  = ((ln >> 5) << 3) + e;
                const int cout = ln & 31;
                const __hip_bfloat16 h =
                    __float2bfloat16(Wg[(tap * CIN + cin) * COUT + cout]);
                v = *(const short*)&h;
            }
            wimg[i] = v;
        }
    }
}

// Per wave: 32 points x 32 cout via 27x v_mfma_f32_32x32x16_bf16.
// Symmetric A/B fragment packing (cin = (lane>>5)*8 + e on both sides) so the
// HW k-permutation cancels — verified rounds 2-4.
template<bool USE_WS>
__global__ __launch_bounds__(BLK, 5) void sct_mfma_kernel(
    const float* __restrict__ feat,            // [N,16] fp32
    const __hip_bfloat16* __restrict__ featb,  // [N,16] bf16 (ws)
    const short* __restrict__ wimg,            // prepacked B-fragment image (ws)
    const float* __restrict__ Wg,              // [27,16,32] fp32 (fallback path)
    const float* __restrict__ bias,            // [32]
    const int*   __restrict__ nbr,             // [N,27]
    float*       __restrict__ out)             // [N,32]
{
    __shared__ short bpack[WIMG_PAD];          // 28672 B -> 5 blocks/CU by LDS

    const int tid = threadIdx.x;
    if (USE_WS) {
        // coalesced image copy: 7 x 16 B per thread
        #pragma unroll
        for (int q = 0; q < 7; ++q) {
            const int off = q * (256 * 8) + tid * 8;        // in shorts
            *(short8v*)&bpack[off] = *(const short8v*)&wimg[off];
        }
    } else {
        for (int i = tid; i < WIMG_SHORTS; i += BLK) {
            const int tap  = i >> 9;
            const int r    = i & 511;
            const int ln   = r >> 3;
            const int e    = r & 7;
            const int cin  = ((ln >> 5) << 3) + e;
            const int cout = ln & 31;
            const __hip_bfloat16 h =
                __float2bfloat16(Wg[(tap * CIN + cin) * COUT + cout]);
            bpack[i] = *(const short*)&h;
        }
    }
    __syncthreads();

    const int lane = tid & 63;
    const int wv   = tid >> 6;                        // 0..3
    const int p0   = blockIdx.x * 128 + wv * 32;      // this wave's 32 points
    const int prow = lane & 31;                       // A-row (point) / B-col (cout)
    const int g    = lane >> 5;                       // k-group
    const int* nb  = nbr + (long)(p0 + prow) * NTAPS;

    // all 27 neighbor ids up front: loads issued back-to-back, one wait
    int nid[NTAPS];
    #pragma unroll
    for (int q = 0; q < 6; ++q) {
        const int4 v = *(const int4*)(nb + 4 * q);
        nid[4*q+0] = v.x; nid[4*q+1] = v.y; nid[4*q+2] = v.z; nid[4*q+3] = v.w;
    }
    {
        const int2 v2 = *(const int2*)(nb + 24);
        nid[24] = v2.x; nid[25] = v2.y; nid[26] = nb[26];
    }

    f32x16 acc;
    {
        const float b = bias[prow];
        #pragma unroll
        for (int r2 = 0; r2 < 16; ++r2) acc[r2] = b;
    }

    short8v af[DEPTH];

    auto gather1 = [&](int t, short8v& dst) {
        const int id = nid[t];
        short8v a = {};
        if (id >= 0) {                                 // exec-masked (~12.5% valid)
            if (USE_WS) {
                a = *(const short8v*)(featb + (long)id * CIN + g * 8);
            } else {
                const float4* fp = (const float4*)(feat + (long)id * CIN + g * 8);
                const float4 x = fp[0];
                const float4 y = fp[1];
                union { short8v v; __hip_bfloat162 h[4]; } u;
                u.h[0] = __float22bfloat162_rn(float2{x.x, x.y});
                u.h[1] = __float22bfloat162_rn(float2{x.z, x.w});
                u.h[2] = __float22bfloat162_rn(float2{y.x, y.y});
                u.h[3] = __float22bfloat162_rn(float2{y.z, y.w});
                a = u.v;
            }
        }
        dst = a;
    };

    #pragma unroll
    for (int t = 0; t < DEPTH; ++t) gather1(t, af[t]);

    #pragma unroll
    for (int t = 0; t < NTAPS; ++t) {
        const short8v bf = *(const short8v*)&bpack[(t << 9) + (lane << 3)];
        acc = __builtin_amdgcn_mfma_f32_32x32x16_bf16(af[t % DEPTH], bf, acc, 0, 0, 0);
        if (t + DEPTH < NTAPS) gather1(t + DEPTH, af[(t + DEPTH) % DEPTH]);
    }

    // D: col = lane&31 (cout), row = (reg&3) + 8*(reg>>2) + 4*(lane>>5) (point)
    #pragma unroll
    for (int r2 = 0; r2 < 16; ++r2) {
        const int row = (r2 & 3) + 8 * (r2 >> 2) + 4 * g;
        out[(long)(p0 + row) * COUT + prow] = acc[r2];
    }
}

extern "C" void kernel_launch(void* const* d_in, const int* in_sizes, int n_in,
                              void* d_out, int out_size, void* d_ws, size_t ws_size,
                              hipStream_t stream) {
    const float* feat = (const float*)d_in[0];
    const float* Wg   = (const float*)d_in[1];
    const float* bias = (const float*)d_in[2];
    const int*   nbr  = (const int*)d_in[3];
    float*       out  = (float*)d_out;

    const size_t need = FEATB_OFF + (size_t)NPTS * CIN * sizeof(__hip_bfloat16);
    if (ws_size >= need) {
        short* wimg = (short*)d_ws;
        __hip_bfloat16* fb = (__hip_bfloat16*)((char*)d_ws + FEATB_OFF);
        prep_kernel<<<NPTS * CIN / 4 / 256 + 1, 256, 0, stream>>>(feat, Wg, wimg, fb);
        sct_mfma_kernel<true><<<NPTS / 128, BLK, 0, stream>>>(
            feat, fb, wimg, Wg, bias, nbr, out);
    } else {
        sct_mfma_kernel<false><<<NPTS / 128, BLK, 0, stream>>>(
            feat, nullptr, nullptr, Wg, bias, nbr, out);
    }
}

// Round 6
// 44.156 us; speedup vs baseline: 1.1229x; 1.1229x over previous
//
#include <hip/hip_runtime.h>
#include <hip/hip_bf16.h>

#define NPTS  262144
#define CIN   16
#define COUT  32
#define NTAPS 27
#define BLK   512
#define DEPTH 12            // gathers in flight per wave (ring buffers)

typedef __attribute__((ext_vector_type(8)))  short short8v;   // 8 bf16 (4 VGPRs)
typedef __attribute__((ext_vector_type(16))) float f32x16;    // MFMA accumulator

// Prep: fb[0..15] = zero row; fb[16 + i] = bf16(feat[i]).  One float4/thread.
__global__ __launch_bounds__(256) void cvt_feat_kernel(
    const float* __restrict__ feat, __hip_bfloat16* __restrict__ fb)
{
    const int i = blockIdx.x * 256 + threadIdx.x;
    const float4 x = ((const float4*)feat)[i];
    __hip_bfloat162* o = (__hip_bfloat162*)(fb + CIN);   // shifted by zero row
    o[2 * i]     = __float22bfloat162_rn(float2{x.x, x.y});
    o[2 * i + 1] = __float22bfloat162_rn(float2{x.z, x.w});
    if (blockIdx.x == 0 && threadIdx.x < 2)
        ((int4*)fb)[threadIdx.x] = int4{0, 0, 0, 0};     // 32B zero row
}

// Per wave: 32 points x 32 cout via 27x v_mfma_f32_32x32x16_bf16.
// Symmetric A/B fragment packing (cin = (lane>>5)*8 + e on both sides) so the
// HW k-permutation cancels — verified rounds 2-5.
// This round: BRANCHLESS gathers. featb has a zero row at index -1 (base is
// shifted by one row), so id=-1 gathers exact zeros; no exec-mask branching
// around the loads -> the 12-deep ring pipelines as a straight load stream.
template<bool USE_WS>
__global__ __launch_bounds__(BLK, 3) void sct_mfma_kernel(
    const float* __restrict__ feat,            // [N,16] fp32 (fallback)
    const __hip_bfloat16* __restrict__ featb,  // zero row + [N,16] bf16 (ws)
    const float* __restrict__ Wg,              // [27,16,32] fp32
    const float* __restrict__ bias,            // [32]
    const int*   __restrict__ nbr,             // [N,27]
    float*       __restrict__ out)             // [N,32]
{
    __shared__ short bpack[NTAPS * 512];       // 27648 B, one copy per 8 waves

    const int tid = threadIdx.x;
    for (int i = tid; i < NTAPS * 512; i += BLK) {
        const int tap  = i >> 9;
        const int r    = i & 511;
        const int ln   = r >> 3;
        const int e    = r & 7;
        const int cin  = ((ln >> 5) << 3) + e;
        const int cout = ln & 31;
        const __hip_bfloat16 h = __float2bfloat16(Wg[(tap * CIN + cin) * COUT + cout]);
        bpack[i] = *(const short*)&h;
    }
    __syncthreads();

    const int lane = tid & 63;
    const int wv   = tid >> 6;                        // 0..7
    const int p0   = blockIdx.x * 256 + wv * 32;      // this wave's 32 points
    const int prow = lane & 31;                       // A-row (point) / B-col (cout)
    const int g    = lane >> 5;                       // k-group
    const int* nb  = nbr + (long)(p0 + prow) * NTAPS;

    // all 27 neighbor ids up front: loads issued back-to-back, one wait
    int nid[NTAPS];
    #pragma unroll
    for (int q = 0; q < 6; ++q) {
        const int4 v = *(const int4*)(nb + 4 * q);
        nid[4*q+0] = v.x; nid[4*q+1] = v.y; nid[4*q+2] = v.z; nid[4*q+3] = v.w;
    }
    {
        const int2 v2 = *(const int2*)(nb + 24);
        nid[24] = v2.x; nid[25] = v2.y; nid[26] = nb[26];
    }

    f32x16 acc;
    {
        const float b = bias[prow];
        #pragma unroll
        for (int r2 = 0; r2 < 16; ++r2) acc[r2] = b;
    }

    short8v af[DEPTH];
    const __hip_bfloat16* fshift = featb + CIN;        // row -1 == zero row

    auto gather1 = [&](int t, short8v& dst) {
        if (USE_WS) {
            // unconditional: id=-1 lands in the zero row (g=0: bytes 0-15, g=1: 16-31)
            dst = *(const short8v*)(fshift + (long)nid[t] * CIN + g * 8);
        } else {
            const int id = nid[t];
            short8v a = {};
            if (id >= 0) {
                const float4* fp = (const float4*)(feat + (long)id * CIN + g * 8);
                const float4 x = fp[0];
                const float4 y = fp[1];
                union { short8v v; __hip_bfloat162 h[4]; } u;
                u.h[0] = __float22bfloat162_rn(float2{x.x, x.y});
                u.h[1] = __float22bfloat162_rn(float2{x.z, x.w});
                u.h[2] = __float22bfloat162_rn(float2{y.x, y.y});
                u.h[3] = __float22bfloat162_rn(float2{y.z, y.w});
                a = u.v;
            }
            dst = a;
        }
    };

    // prologue: 12 gathers in flight
    #pragma unroll
    for (int t = 0; t < DEPTH; ++t) gather1(t, af[t]);

    // steady state: consume tap t, refill slot with tap t+12
    #pragma unroll
    for (int t = 0; t < NTAPS; ++t) {
        const short8v bf = *(const short8v*)&bpack[(t << 9) + (lane << 3)];
        acc = __builtin_amdgcn_mfma_f32_32x32x16_bf16(af[t % DEPTH], bf, acc, 0, 0, 0);
        if (t + DEPTH < NTAPS) gather1(t + DEPTH, af[(t + DEPTH) % DEPTH]);
    }

    // D: col = lane&31 (cout), row = (reg&3) + 8*(reg>>2) + 4*(lane>>5) (point)
    #pragma unroll
    for (int r2 = 0; r2 < 16; ++r2) {
        const int row = (r2 & 3) + 8 * (r2 >> 2) + 4 * g;
        out[(long)(p0 + row) * COUT + prow] = acc[r2];
    }
}

extern "C" void kernel_launch(void* const* d_in, const int* in_sizes, int n_in,
                              void* d_out, int out_size, void* d_ws, size_t ws_size,
                              hipStream_t stream) {
    const float* feat = (const float*)d_in[0];
    const float* Wg   = (const float*)d_in[1];
    const float* bias = (const float*)d_in[2];
    const int*   nbr  = (const int*)d_in[3];
    float*       out  = (float*)d_out;

    const size_t need = (size_t)(NPTS + 1) * CIN * sizeof(__hip_bfloat16);  // 8 MB + row
    if (ws_size >= need) {
        __hip_bfloat16* fb = (__hip_bfloat16*)d_ws;
        cvt_feat_kernel<<<NPTS * CIN / 4 / 256, 256, 0, stream>>>(feat, fb);
        sct_mfma_kernel<true><<<NPTS / 256, BLK, 0, stream>>>(feat, fb, Wg, bias, nbr, out);
    } else {
        sct_mfma_kernel<false><<<NPTS / 256, BLK, 0, stream>>>(feat, nullptr, Wg, bias, nbr, out);
    }
}